// Round 6
// baseline (224.168 us; speedup 1.0000x reference)
//
#include <hip/hip_runtime.h>
#include <hip/hip_bf16.h>

// Problem constants
constexpr int B  = 128;
constexpr int C  = 235;
constexpr int N  = 21;
constexpr int HW = 4096;   // 64*64
constexpr int HO = 128;    // heads*fo
constexpr int E  = 41;     // 20 skeleton edges + 21 self loops

typedef __attribute__((ext_vector_type(8)))  short  short8;   // 8 bf16 (4 VGPRs)
typedef __attribute__((ext_vector_type(16))) float  f32x16;   // 32x32 accum

__device__ inline unsigned short bf16r(float x) {
    return __bfloat16_as_ushort(__float2bfloat16(x));   // RNE
}

// ---------------- K1: q[b,n,c] = sum_p t[b,n,p] * f[b,c,p] ----------------
// v6: direct-from-global MFMA (v4 structure, which tied v5's staged LDS) but
// with 2x the blocks for MLP/occupancy: each wave owns ONE 32-col tile,
// grid = 2 cg x 8 ks x 128 b = 2048 blocks (8 blocks/CU), explicit register
// prefetch of the next iteration's 4 loads, chunked XCD mapping so blocks
// sharing a (b,ks) t-slice land on one XCD's L2.
constexpr int KSPLIT = 8;
constexpr int KRANGE = HW / KSPLIT;   // 512
constexpr int NSLOT  = KSPLIT;

__global__ __launch_bounds__(256) void k1_qgemm(
    const float* __restrict__ f,   // [B][C][HW]
    const float* __restrict__ t,   // [B][N][HW]
    float* __restrict__ qp)        // [NSLOT][B][N][C] partials
{
    const int j = blockIdx.x;                    // 0..2047
    const int logical = (j & 7) * 256 + (j >> 3);  // chunked XCD mapping
    const int cg = logical & 1;
    const int ks = (logical >> 1) & 7;
    const int b  = logical >> 4;

    const int tid  = threadIdx.x;
    const int wave = tid >> 6;
    const int lane = tid & 63;
    const int l31  = lane & 31;
    const int kh   = lane >> 5;      // k-half of 16-k MFMA step

    const float* fb = f + (size_t)b * C * HW;
    const float* tb = t + (size_t)b * N * HW;

    const int arow = (l31 < N) ? l31 : (N - 1);
    const int col  = cg * 128 + wave * 32 + l31;
    const int colc = (col < C) ? col : (C - 1);

    const float* pa = tb + (size_t)arow * HW + kh * 8;
    const float* pb = fb + (size_t)colc * HW + kh * 8;

    f32x16 acc = {};
    const int kbase = ks * KRANGE;
    const int kend  = kbase + KRANGE;

    float4 A0 = *reinterpret_cast<const float4*>(pa + kbase);
    float4 A1 = *reinterpret_cast<const float4*>(pa + kbase + 4);
    float4 B0 = *reinterpret_cast<const float4*>(pb + kbase);
    float4 B1 = *reinterpret_cast<const float4*>(pb + kbase + 4);

    #pragma unroll 4
    for (int k = kbase; k < kend; k += 16) {
        const float4 a0 = A0, a1 = A1, b0 = B0, b1 = B1;
        if (k + 16 < kend) {          // prefetch next iteration
            A0 = *reinterpret_cast<const float4*>(pa + k + 16);
            A1 = *reinterpret_cast<const float4*>(pa + k + 20);
            B0 = *reinterpret_cast<const float4*>(pb + k + 16);
            B1 = *reinterpret_cast<const float4*>(pb + k + 20);
        }
        union { short8 v; unsigned short u[8]; } av, bv;
        av.u[0] = bf16r(a0.x); av.u[1] = bf16r(a0.y);
        av.u[2] = bf16r(a0.z); av.u[3] = bf16r(a0.w);
        av.u[4] = bf16r(a1.x); av.u[5] = bf16r(a1.y);
        av.u[6] = bf16r(a1.z); av.u[7] = bf16r(a1.w);
        bv.u[0] = bf16r(b0.x); bv.u[1] = bf16r(b0.y);
        bv.u[2] = bf16r(b0.z); bv.u[3] = bf16r(b0.w);
        bv.u[4] = bf16r(b1.x); bv.u[5] = bf16r(b1.y);
        bv.u[6] = bf16r(b1.z); bv.u[7] = bf16r(b1.w);
        acc = __builtin_amdgcn_mfma_f32_32x32x16_bf16(av.v, bv.v, acc, 0, 0, 0);
    }

    // C/D layout (verified): col = lane&31, row = (reg&3) + 8*(reg>>2) + 4*(lane>>5)
    float* qpk = qp + ((size_t)ks * B + b) * N * C;
    #pragma unroll
    for (int reg = 0; reg < 16; reg++) {
        const int row = (reg & 3) + 8 * (reg >> 2) + 4 * kh;
        if (row < N && col < C)
            qpk[row * C + col] = acc[reg];
    }
}

// ---------------- K1b: reduce partials -> q, plus per-(b,n) BN sums ----------------
__global__ __launch_bounds__(256) void k1b_bn(
    const float* __restrict__ qp,  // [NSLOT][B][N][C]
    float* __restrict__ q,         // [B][N][C]
    float* __restrict__ bnp)       // [B][N][2] partial {sum, sumsq}
{
    const int b    = blockIdx.x;
    const int tid  = threadIdx.x;
    const int wave = tid >> 6;
    const int lane = tid & 63;
    __shared__ float rs[N][4], rs2[N][4];
    constexpr int S = B * N * C;

    for (int n = 0; n < N; ++n) {
        float v = 0.f;
        const int idx = (b * N + n) * C + tid;
        if (tid < C) {
            #pragma unroll
            for (int p = 0; p < NSLOT; p++) v += qp[(size_t)p * S + idx];
            q[idx] = v;
        }
        float s = v, s2 = v * v;
        for (int off = 32; off; off >>= 1) {
            s  += __shfl_down(s,  off);
            s2 += __shfl_down(s2, off);
        }
        if (lane == 0) { rs[n][wave] = s; rs2[n][wave] = s2; }
    }
    __syncthreads();
    if (tid < N) {
        const float S1 = rs[tid][0] + rs[tid][1] + rs[tid][2] + rs[tid][3];
        const float S2 = rs2[tid][0] + rs2[tid][1] + rs2[tid][2] + rs2[tid][3];
        bnp[(b * N + tid) * 2]     = S1;
        bnp[(b * N + tid) * 2 + 1] = S2;
    }
}

// ---------------- K3: stats + BN-apply + LeakyReLU + GAT + Cheb ----------------
__global__ __launch_bounds__(256) void k3_tail(
    const float* __restrict__ q,        // [B][N][C]
    const float* __restrict__ bnp,      // [B][N][2]
    const float* __restrict__ gamma,    // [N]
    const float* __restrict__ beta,     // [N]
    const float* __restrict__ gatw,     // [C][HO]
    const float* __restrict__ attsrc,   // [4][32]
    const float* __restrict__ attdst,   // [4][32]
    const float* __restrict__ gatbias,  // [HO]
    const float* __restrict__ chebw,    // [2][HO][3]
    const float* __restrict__ chebbias, // [3]
    const float* __restrict__ adj,      // [N][N]
    const int* __restrict__ esrc,
    const int* __restrict__ edst,
    float* __restrict__ out)            // [B][N][3]
{
    __shared__ float ql[N][C + 1];
    __shared__ float Wl[48][HO];
    __shared__ float hl[N][HO];
    __shared__ float xl[N][HO];
    __shared__ float stl[N][2];
    __shared__ float asrcl[N][4], adstl[N][4];
    __shared__ float el[E][4], alphal[E][4];
    __shared__ float mx[N][4], den[N][4];
    __shared__ float zl[N][3], t0l[N][3], dsl[N];
    __shared__ int esl[E], edl[E];

    const int b = blockIdx.x;
    const int tid = threadIdx.x;

    // finalize BN stats (redundant per block; 21 threads x 256 small loads)
    if (tid < N) {
        float S1 = 0.f, S2 = 0.f;
        for (int bb = 0; bb < B; bb++) {
            S1 += bnp[(bb * N + tid) * 2];
            S2 += bnp[(bb * N + tid) * 2 + 1];
        }
        const float cnt  = (float)(B * C);
        const float mean = S1 / cnt;
        const float var  = S2 / cnt - mean * mean;
        const float sc   = gamma[tid] * rsqrtf(var + 1e-5f);
        stl[tid][0] = sc;
        stl[tid][1] = beta[tid] - mean * sc;
    }
    if (tid < E) { esl[tid] = esrc[tid]; edl[tid] = edst[tid]; }
    __syncthreads();

    for (int v = tid; v < N * C; v += 256) {
        const int n = v / C, c = v % C;
        float x = q[((size_t)b * N + n) * C + c];
        x = x * stl[n][0] + stl[n][1];
        ql[n][c] = (x >= 0.f) ? x : 0.1f * x;
    }
    for (int v = tid; v < N * HO; v += 256) hl[v >> 7][v & 127] = 0.f;
    __syncthreads();

    for (int k0 = 0; k0 < C; k0 += 48) {
        const int kc = (C - k0) < 48 ? (C - k0) : 48;
        for (int v = tid; v < kc * HO; v += 256) {
            const int kk = v >> 7, o = v & 127;
            Wl[kk][o] = gatw[(size_t)(k0 + kk) * HO + o];
        }
        __syncthreads();
        for (int idx = tid; idx < N * HO; idx += 256) {
            const int n = idx >> 7, o = idx & 127;
            float s = hl[n][o];
            for (int kk = 0; kk < kc; kk++)
                s += ql[n][k0 + kk] * Wl[kk][o];
            hl[n][o] = s;
        }
        __syncthreads();
    }

    if (tid < N * 4) {
        const int n = tid >> 2, h = tid & 3;
        float ss = 0.f, sd = 0.f;
        for (int fo = 0; fo < 32; fo++) {
            const float hv = hl[n][h * 32 + fo];
            ss += hv * attsrc[h * 32 + fo];
            sd += hv * attdst[h * 32 + fo];
        }
        asrcl[n][h] = ss; adstl[n][h] = sd;
    }
    __syncthreads();
    if (tid < E * 4) {
        const int e = tid >> 2, h = tid & 3;
        const float v = asrcl[esl[e]][h] + adstl[edl[e]][h];
        el[e][h] = (v >= 0.f) ? v : 0.2f * v;
    }
    __syncthreads();
    if (tid < N * 4) {
        const int n = tid >> 2, h = tid & 3;
        float m = -1e30f;
        for (int e = 0; e < E; e++)
            if (edl[e] == n) m = fmaxf(m, el[e][h]);
        mx[n][h] = m;
    }
    __syncthreads();
    if (tid < E * 4) {
        const int e = tid >> 2, h = tid & 3;
        el[e][h] = __expf(el[e][h] - mx[edl[e]][h]);
    }
    __syncthreads();
    if (tid < N * 4) {
        const int n = tid >> 2, h = tid & 3;
        float s = 0.f;
        for (int e = 0; e < E; e++)
            if (edl[e] == n) s += el[e][h];
        den[n][h] = s;
    }
    __syncthreads();
    if (tid < E * 4) {
        const int e = tid >> 2, h = tid & 3;
        alphal[e][h] = el[e][h] / den[edl[e]][h];
    }
    __syncthreads();

    for (int idx = tid; idx < N * HO; idx += 256) {
        const int n = idx >> 7, o = idx & 127, h = o >> 5;
        float s = 0.f;
        for (int e = 0; e < E; e++)
            if (edl[e] == n) s += alphal[e][h] * hl[esl[e]][o];
        xl[n][o] = s + gatbias[o];
    }
    if (tid < N) {
        float s = 0.f;
        for (int j2 = 0; j2 < N; j2++) s += adj[tid * N + j2];
        dsl[tid] = rsqrtf(s);
    }
    __syncthreads();

    if (tid < N * 3) {
        const int n = tid / 3, o = tid % 3;
        float s0 = 0.f, sz = 0.f;
        for (int c2 = 0; c2 < HO; c2++) {
            const float xv = xl[n][c2];
            s0 += xv * chebw[(size_t)c2 * 3 + o];
            sz += xv * chebw[(size_t)(HO + c2) * 3 + o];
        }
        t0l[n][o] = s0; zl[n][o] = sz;
    }
    __syncthreads();
    if (tid < N * 3) {
        const int m = tid / 3, o = tid % 3;
        float s = t0l[m][o] + zl[m][o];
        for (int n2 = 0; n2 < N; n2++)
            s -= dsl[m] * adj[m * N + n2] * dsl[n2] * zl[n2][o];
        out[(size_t)b * N * 3 + tid] = s + chebbias[o];
    }
}

extern "C" void kernel_launch(void* const* d_in, const int* in_sizes, int n_in,
                              void* d_out, int out_size, void* d_ws, size_t ws_size,
                              hipStream_t stream) {
    const float* feature  = (const float*)d_in[0];
    const float* target   = (const float*)d_in[1];
    const float* gamma    = (const float*)d_in[2];
    const float* beta     = (const float*)d_in[3];
    const float* gatw     = (const float*)d_in[4];
    const float* attsrc   = (const float*)d_in[5];
    const float* attdst   = (const float*)d_in[6];
    const float* gatbias  = (const float*)d_in[7];
    const float* chebw    = (const float*)d_in[8];
    const float* chebbias = (const float*)d_in[9];
    const float* adj      = (const float*)d_in[10];
    const int*   esrc     = (const int*)d_in[11];
    const int*   edst     = (const int*)d_in[12];

    constexpr int QS = B * N * C;
    float* qp  = (float*)d_ws;                 // [NSLOT][B][N][C]
    float* q   = qp + (size_t)NSLOT * QS;      // [B][N][C]
    float* bnp = q + QS;                       // [B][N][2]
    float* out = (float*)d_out;

    hipLaunchKernelGGL(k1_qgemm, dim3(2 * KSPLIT * B), dim3(256), 0, stream,
                       feature, target, qp);
    hipLaunchKernelGGL(k1b_bn, dim3(B), dim3(256), 0, stream, qp, q, bnp);
    hipLaunchKernelGGL(k3_tail, dim3(B), dim3(256), 0, stream,
                       q, bnp, gamma, beta, gatw, attsrc, attdst, gatbias,
                       chebw, chebbias, adj, esrc, edst, out);
}